// Round 19
// baseline (336.861 us; speedup 1.0000x reference)
//
#include <hip/hip_runtime.h>
#include <hip/hip_bf16.h>
#include <stdint.h>

#define B_ 4
#define T_ 2048
#define D_ 1024
#define H_ 16
#define DK_ 64
#define M_ (B_*T_)   // 8192

typedef __attribute__((ext_vector_type(8))) short bf16x8;
typedef __attribute__((ext_vector_type(4))) short bf16x4;
typedef __attribute__((ext_vector_type(4))) float f32x4;
typedef __hip_bfloat16 bf16;

__device__ __forceinline__ void gld_lds16(const bf16* g, bf16* l) {
  __builtin_amdgcn_global_load_lds((const __attribute__((address_space(1))) void*)g,
                                   (__attribute__((address_space(3))) void*)l,
                                   16, 0, 0);
}
__device__ __forceinline__ void gld_lds16f(const float* g, float* l) {
  __builtin_amdgcn_global_load_lds((const __attribute__((address_space(1))) void*)g,
                                   (__attribute__((address_space(3))) void*)l,
                                   16, 0, 0);
}

__device__ __forceinline__ short bfbits(float f) {
  union { bf16 h; short s; } u; u.h = __float2bfloat16(f); return u.s;
}

// ---------------------------------------------------------------------------
// fp32 -> bf16 convert, WEIGHTS ONLY (round-18 exact)
// ---------------------------------------------------------------------------
__global__ __launch_bounds__(256) void cvt_w(
    const float* __restrict__ wq, const float* __restrict__ wk,
    const float* __restrict__ wv, const float* __restrict__ wo,
    bf16* __restrict__ wqb, bf16* __restrict__ wkb,
    bf16* __restrict__ wvb, bf16* __restrict__ wob) {
  int gid = blockIdx.x * 256 + threadIdx.x;   // 0 .. 1048575 (float4 units)
  int s = gid >> 18, off = gid & 262143;
  const float* src = (s == 0) ? wq : (s == 1) ? wk : (s == 2) ? wv : wo;
  bf16* dst = (s == 0) ? wqb : (s == 1) ? wkb : (s == 2) ? wvb : wob;
  float4 val = reinterpret_cast<const float4*>(src)[off];
  union { ushort4 u; bf16 h[4]; } o;
  o.h[0] = __float2bfloat16(val.x);
  o.h[1] = __float2bfloat16(val.y);
  o.h[2] = __float2bfloat16(val.z);
  o.h[3] = __float2bfloat16(val.w);
  reinterpret_cast<ushort4*>(dst)[off] = o.u;
}

// ---------------------------------------------------------------------------
// Unified QKV projection (round-18 exact)
// ---------------------------------------------------------------------------
__global__ __launch_bounds__(512) void proj_qkv(
    const float* __restrict__ qf, const float* __restrict__ kf, const float* __restrict__ vf,
    const bf16* __restrict__ Wqb, const bf16* __restrict__ Wkb, const bf16* __restrict__ Wvb,
    const float* __restrict__ bq, const float* __restrict__ bk, const float* __restrict__ bv,
    bf16* __restrict__ Qh, bf16* __restrict__ Kh, bf16* __restrict__ Vt) {
  constexpr int K = 1024;
  constexpr int BK = 64;
  __shared__ __align__(16) bf16  As[256 * 64];
  __shared__ __align__(16) float Bsf[128 * 64];

  const int z = blockIdx.z;
  const bf16*  A  = (z == 0) ? Wqb : (z == 1) ? Wkb : Wvb;
  const float* Bf = (z == 0) ? qf : (z == 1) ? kf : vf;
  const float* bias = (z == 0) ? bq : (z == 1) ? bk : bv;
  bf16* out = (z == 0) ? Qh : (z == 1) ? Kh : Vt;
  const float scale = (z == 0) ? 0.125f * 1.4426950408889634f : 1.0f;

  const int bid = blockIdx.x + 32 * blockIdx.y;
  const int bm = bid >> 6;
  const int bn = bid & 63;

  const int tid = threadIdx.x;
  const int w = tid >> 6, l = tid & 63;
  const int wm = w >> 1, wn = w & 1;
  const int lr = l & 15, lk = l >> 4;

  f32x4 acc[4][4] = {};

  for (int k0 = 0; k0 < K; k0 += BK) {
#pragma unroll
    for (int i = 0; i < 4; ++i) {
      int p = i * 512 + tid;
      int row = p >> 3;
      int so = (p & 7) ^ (row & 7);
      gld_lds16(A + (size_t)(bm * 256 + row) * K + k0 + so * 8, &As[p * 8]);
    }
#pragma unroll
    for (int i = 0; i < 4; ++i) {
      int p = i * 512 + tid;
      int row = p >> 4;
      int sc = (p & 15) ^ (row & 15);
      gld_lds16f(Bf + (size_t)(bn * 128 + row) * K + k0 + sc * 4, &Bsf[p * 4]);
    }
    __syncthreads();

#pragma unroll
    for (int kk = 0; kk < 2; ++kk) {
      bf16x8 af[4], bfr[4];
#pragma unroll
      for (int m = 0; m < 4; ++m) {
        int row = wm * 64 + m * 16 + lr;
        int slot = (kk * 4 + lk) ^ (row & 7);
        af[m] = *reinterpret_cast<const bf16x8*>(&As[row * 64 + slot * 8]);
      }
#pragma unroll
      for (int n = 0; n < 4; ++n) {
        int trow = wn * 64 + n * 16 + lr;
        int c0 = kk * 8 + lk * 2;
        int s0 = c0 ^ (trow & 15);
        int s1 = (c0 + 1) ^ (trow & 15);
        f32x4 lo = *reinterpret_cast<const f32x4*>(&Bsf[trow * 64 + s0 * 4]);
        f32x4 hi = *reinterpret_cast<const f32x4*>(&Bsf[trow * 64 + s1 * 4]);
        bf16x8 bb;
        bb[0] = bfbits(lo[0]); bb[1] = bfbits(lo[1]);
        bb[2] = bfbits(lo[2]); bb[3] = bfbits(lo[3]);
        bb[4] = bfbits(hi[0]); bb[5] = bfbits(hi[1]);
        bb[6] = bfbits(hi[2]); bb[7] = bfbits(hi[3]);
        bfr[n] = bb;
      }
      __builtin_amdgcn_s_setprio(1);
#pragma unroll
      for (int m = 0; m < 4; ++m)
#pragma unroll
        for (int n = 0; n < 4; ++n)
          acc[m][n] = __builtin_amdgcn_mfma_f32_16x16x32_bf16(af[m], bfr[n], acc[m][n], 0, 0, 0);
      __builtin_amdgcn_s_setprio(0);
    }
    __syncthreads();
  }

  const int crow0 = bm * 256 + wm * 64;
  const int ccol0 = bn * 128 + wn * 64;
  if (z < 2) {
#pragma unroll
    for (int m = 0; m < 4; ++m) {
#pragma unroll
      for (int n = 0; n < 4; ++n) {
        const int row0 = crow0 + m * 16 + lk * 4;
        const int col = ccol0 + n * 16 + lr;
        bf16x4 pk;
#pragma unroll
        for (int r = 0; r < 4; ++r)
          pk[r] = bfbits((acc[m][n][r] + bias[row0 + r]) * scale);
        size_t idx = (((size_t)(col >> 11) * H_ + (row0 >> 6)) * T_ + (col & (T_ - 1))) * DK_ + (row0 & 63);
        *reinterpret_cast<bf16x4*>(&out[idx]) = pk;
      }
    }
  } else {
#pragma unroll
    for (int m = 0; m < 4; ++m) {
#pragma unroll
      for (int n = 0; n < 4; ++n) {
#pragma unroll
        for (int r = 0; r < 4; ++r) {
          const int row = crow0 + m * 16 + lk * 4 + r;
          const int col = ccol0 + n * 16 + lr;
          float vv = acc[m][n][r] + bias[row];
          size_t idx = (size_t)(col >> 11) * ((size_t)H_ * DK_ * T_) + (size_t)row * T_ + (col & (T_ - 1));
          out[idx] = __float2bfloat16(vv);
        }
      }
    }
  }
}

// ---------------------------------------------------------------------------
// Output GEMM (round-18 exact)
// ---------------------------------------------------------------------------
__global__ __launch_bounds__(512) void gemm_out(const bf16* __restrict__ A,
                                                const bf16* __restrict__ Bm,
                                                const float* __restrict__ bias,
                                                float* __restrict__ Cout) {
  constexpr int K = 1024;
  constexpr int BK = 64;
  __shared__ __align__(16) bf16 As[256 * BK];
  __shared__ __align__(16) bf16 Bs[128 * BK];

  const int bid = blockIdx.x + 32 * blockIdx.y;
  const int xcd = bid & 7, loc = bid >> 3;
  const int bm = xcd * 4 + (loc & 3);
  const int bn = loc >> 2;

  const int tid = threadIdx.x;
  const int w = tid >> 6, l = tid & 63;
  const int wm = w >> 1, wn = w & 1;
  const int lr = l & 15, lk = l >> 4;

  f32x4 acc[4][4] = {};

  for (int k0 = 0; k0 < K; k0 += BK) {
#pragma unroll
    for (int i = 0; i < 4; ++i) {
      int p = i * 512 + tid;
      int row = p >> 3;
      int so = (p & 7) ^ (row & 7);
      gld_lds16(A + (size_t)(bm * 256 + row) * K + k0 + so * 8, &As[p * 8]);
    }
#pragma unroll
    for (int i = 0; i < 2; ++i) {
      int p = i * 512 + tid;
      int row = p >> 3;
      int so = (p & 7) ^ (row & 7);
      gld_lds16(Bm + (size_t)(bn * 128 + row) * K + k0 + so * 8, &Bs[p * 8]);
    }
    __syncthreads();

#pragma unroll
    for (int kk = 0; kk < 2; ++kk) {
      bf16x8 af[4], bfr[4];
#pragma unroll
      for (int m = 0; m < 4; ++m) {
        int row = wm * 64 + m * 16 + lr;
        int slot = (kk * 4 + lk) ^ (row & 7);
        af[m] = *reinterpret_cast<const bf16x8*>(&As[row * BK + slot * 8]);
      }
#pragma unroll
      for (int n = 0; n < 4; ++n) {
        int row = wn * 64 + n * 16 + lr;
        int slot = (kk * 4 + lk) ^ (row & 7);
        bfr[n] = *reinterpret_cast<const bf16x8*>(&Bs[row * BK + slot * 8]);
      }
#pragma unroll
      for (int m = 0; m < 4; ++m)
#pragma unroll
        for (int n = 0; n < 4; ++n)
          acc[m][n] = __builtin_amdgcn_mfma_f32_16x16x32_bf16(af[m], bfr[n], acc[m][n], 0, 0, 0);
    }
    __syncthreads();
  }

  const int crow0 = bm * 256 + wm * 64;
  const int ccol0 = bn * 128 + wn * 64;
#pragma unroll
  for (int m = 0; m < 4; ++m) {
#pragma unroll
    for (int n = 0; n < 4; ++n) {
#pragma unroll
      for (int r = 0; r < 4; ++r) {
        const int row = crow0 + m * 16 + lk * 4 + r;
        const int col = ccol0 + n * 16 + lr;
        Cout[(size_t)row * D_ + col] = acc[m][n][r] + bias[col];
      }
    }
  }
}

// ---------------------------------------------------------------------------
// Causal flash attention v14: TWO 16-row groups per wave (block = 128 q-rows),
// KVBLK=32. K/V fragment reads + staging + barriers SHARED across groups ->
// per unit work: block-iters, barriers, stage issues, K/V ds_reads all halve
// vs r12; softmax VALU per work unchanged. LDS 26 KB -> 6 blocks/CU (occupancy
// preserved, unlike the failed r10 2-blocks/CU attempt).
// Grid 1024 = 64 heads x 16 heavy-first tasks; head = bid&63 (XCD pinning).
// Both groups share diagonal tile jd (base 32-aligned).
// ---------------------------------------------------------------------------
__global__ __launch_bounds__(256, 6) void attn_fwd(const bf16* __restrict__ Qh,
                                                   const bf16* __restrict__ Kh,
                                                   const bf16* __restrict__ Vt,
                                                   bf16* __restrict__ ctx) {
  __shared__ __align__(16) bf16 Kbuf[2][32 * 64];   // 8 KB
  __shared__ __align__(16) bf16 Vbuf[2][32 * 64];   // 8 KB (packed 2 dk/row)
  __shared__ __align__(16) char Ps[4][2][16 * 80];  // 10 KB

  const int tid = threadIdx.x, w = tid >> 6, l = tid & 63;
  const int lr = l & 15, lk = l >> 4;
  const int bid = blockIdx.x;
  const int head = bid & 63;                 // head%8 == bid%8 -> XCD pinning
  const int t = 15 - (bid >> 6);             // heavy tasks first (128 rows each)

  const bf16* Qb = Qh + (size_t)head * T_ * DK_;
  const bf16* Kb = Kh + (size_t)head * T_ * DK_;
  const bf16* Vb = Vt + (size_t)head * DK_ * T_;
  const int bb = head >> 4, hh = head & 15;

  const int base = t * 128 + w * 32;         // this wave's 32 q-rows
  const int nt32 = 4 * (t + 1);              // KV tiles of 32
  const int jd = base >> 5;                  // shared diagonal tile

  // ---- Q fragments, both groups ----
  bf16x8 qf[2][2];
#pragma unroll
  for (int g = 0; g < 2; ++g) {
    const bf16* qp = Qb + (size_t)(base + g * 16 + lr) * DK_ + lk * 8;
    qf[g][0] = *reinterpret_cast<const bf16x8*>(qp);
    qf[g][1] = *reinterpret_cast<const bf16x8*>(qp + 32);
  }

  // ---- hoisted staging pointers ----
  const int p = tid;
  const int krow = p >> 3, kso = (p & 7) ^ (krow & 7);
  const bf16* kgp = Kb + (size_t)krow * DK_ + kso * 8;
  const int vu = (p & 7) ^ (krow & 7);
  const int vdk = krow * 2 + (vu >> 2);
  const bf16* vgp = Vb + (size_t)vdk * T_ + (vu & 3) * 8;
  bf16* const kl0 = &Kbuf[0][p * 8];
  bf16* const kl1 = &Kbuf[1][p * 8];
  bf16* const vl0 = &Vbuf[0][p * 8];
  bf16* const vl1 = &Vbuf[1][p * 8];

  // ---- hoisted fragment/P offsets ----
  int qko[2][2], pvo[4];
#pragma unroll
  for (int n = 0; n < 2; ++n) {
    const int row = n * 16 + lr;
    qko[n][0] = row * 64 + ((lk ^ (row & 7)) << 3);
    qko[n][1] = row * 64 + (((4 + lk) ^ (row & 7)) << 3);
  }
#pragma unroll
  for (int n = 0; n < 4; ++n) {
    const int rowp = n * 8 + (lr >> 1);
    const int s = ((lr & 1) * 4 + lk) ^ (rowp & 7);
    pvo[n] = rowp * 64 + s * 8;
  }
  char* const Pw0 = &Ps[w][0][0];
  char* const Pw1 = &Ps[w][1][0];
  const int pro = lr * 80 + lk * 16;

  f32x4 oacc[2][4] = {};
  float srow[2] = { 0.f, 0.f };

  // ---- prologue ----
  gld_lds16(kgp, kl0);
  gld_lds16(vgp, vl0);
  kgp += 32 * DK_;
  vgp += 32;
  __syncthreads();

  int buf = 0;
#pragma unroll 1
  for (int j = 0; j < nt32; ++j) {
    if (j + 1 < nt32) {
      gld_lds16(kgp, buf ? kl0 : kl1);
      gld_lds16(vgp, buf ? vl0 : vl1);
      kgp += 32 * DK_;
      vgp += 32;
    }

    if (j <= jd) {
      const bf16* kbase = buf ? &Kbuf[1][0] : &Kbuf[0][0];
      const bf16* vbase = buf ? &Vbuf[1][0] : &Vbuf[0][0];

      // ---- S^T: K fragments shared across both groups ----
      f32x4 sacc[2][2] = {};
      __builtin_amdgcn_s_setprio(1);
#pragma unroll
      for (int n = 0; n < 2; ++n) {
        bf16x8 kf0 = *reinterpret_cast<const bf16x8*>(kbase + qko[n][0]);
        bf16x8 kf1 = *reinterpret_cast<const bf16x8*>(kbase + qko[n][1]);
        sacc[0][n] = __builtin_amdgcn_mfma_f32_16x16x32_bf16(kf0, qf[0][0], sacc[0][n], 0, 0, 0);
        sacc[0][n] = __builtin_amdgcn_mfma_f32_16x16x32_bf16(kf1, qf[0][1], sacc[0][n], 0, 0, 0);
        sacc[1][n] = __builtin_amdgcn_mfma_f32_16x16x32_bf16(kf0, qf[1][0], sacc[1][n], 0, 0, 0);
        sacc[1][n] = __builtin_amdgcn_mfma_f32_16x16x32_bf16(kf1, qf[1][1], sacc[1][n], 0, 0, 0);
      }
      __builtin_amdgcn_s_setprio(0);

      // ---- causal mask on the shared diagonal tile ----
      if (j == jd) {
#pragma unroll
        for (int g = 0; g < 2; ++g) {
          const int qrow = base + g * 16 + lr;
#pragma unroll
          for (int n = 0; n < 2; ++n)
#pragma unroll
            for (int r = 0; r < 4; ++r)
              if (j * 32 + n * 16 + lk * 4 + r > qrow) sacc[g][n][r] = -1e30f;
        }
      }

      // ---- fixed-shift softmax per group ----
      bf16x8 pa[2];
#pragma unroll
      for (int g = 0; g < 2; ++g) {
        char* Pw = g ? Pw1 : Pw0;
        float ts = 0.f;
#pragma unroll
        for (int n = 0; n < 2; ++n) {
          float p0 = __builtin_exp2f(sacc[g][n][0]);
          float p1 = __builtin_exp2f(sacc[g][n][1]);
          float p2 = __builtin_exp2f(sacc[g][n][2]);
          float p3 = __builtin_exp2f(sacc[g][n][3]);
          ts += (p0 + p1) + (p2 + p3);
          bf16x4 pk;
          pk[0] = bfbits(p0); pk[1] = bfbits(p1); pk[2] = bfbits(p2); pk[3] = bfbits(p3);
          *reinterpret_cast<bf16x4*>(Pw + lr * 80 + n * 32 + lk * 8) = pk;
        }
        ts += __shfl_xor(ts, 16, 64);
        ts += __shfl_xor(ts, 32, 64);
        srow[g] += ts;
        pa[g] = *reinterpret_cast<const bf16x8*>(Pw + pro);
      }

      // ---- PV: V fragments shared across both groups ----
      __builtin_amdgcn_s_setprio(1);
#pragma unroll
      for (int n = 0; n < 4; ++n) {
        bf16x8 vf = *reinterpret_cast<const bf16x8*>(vbase + pvo[n]);
        oacc[0][n] = __builtin_amdgcn_mfma_f32_16x16x32_bf16(vf, pa[0], oacc[0][n], 0, 0, 0);
        oacc[1][n] = __builtin_amdgcn_mfma_f32_16x16x32_bf16(vf, pa[1], oacc[1][n], 0, 0, 0);
      }
      __builtin_amdgcn_s_setprio(0);
    }

    __syncthreads();
    buf ^= 1;
  }

  // ---- normalize + packed store (both groups) ----
#pragma unroll
  for (int g = 0; g < 2; ++g) {
    const float inv = 1.0f / srow[g];
    bf16* cp = &ctx[((size_t)(bb * T_ + base + g * 16 + lr)) * D_ + hh * DK_ + lk * 4];
#pragma unroll
    for (int n = 0; n < 4; ++n) {
      bf16x4 pk;
#pragma unroll
      for (int r = 0; r < 4; ++r) pk[r] = bfbits(oacc[g][n][r] * inv);
      *reinterpret_cast<bf16x4*>(cp + n * 16) = pk;
    }
  }
}

// ---------------------------------------------------------------------------
// launch
// ---------------------------------------------------------------------------
extern "C" void kernel_launch(void* const* d_in, const int* in_sizes, int n_in,
                              void* d_out, int out_size, void* d_ws, size_t ws_size,
                              hipStream_t stream) {
  const float* q  = (const float*)d_in[0];
  const float* k  = (const float*)d_in[1];
  const float* v  = (const float*)d_in[2];
  const float* Wq = (const float*)d_in[3];
  const float* Wk = (const float*)d_in[4];
  const float* Wv = (const float*)d_in[5];
  const float* Wo = (const float*)d_in[6];
  const float* bq = (const float*)d_in[7];
  const float* bk = (const float*)d_in[8];
  const float* bv = (const float*)d_in[9];
  const float* bo = (const float*)d_in[10];

  constexpr size_t E_IN = (size_t)M_ * D_;
  constexpr size_t E_W  = (size_t)D_ * D_;
  char* ws = (char*)d_ws;
  size_t off = 0;
  bf16* Wqb = (bf16*)(ws + off); off += E_W * 2;
  bf16* Wkb = (bf16*)(ws + off); off += E_W * 2;
  bf16* Wvb = (bf16*)(ws + off); off += E_W * 2;
  bf16* Wob = (bf16*)(ws + off); off += E_W * 2;
  bf16* Qh  = (bf16*)(ws + off); off += E_IN * 2;
  bf16* Kh  = (bf16*)(ws + off); off += E_IN * 2;
  bf16* Vtw = (bf16*)(ws + off); off += E_IN * 2;
  bf16* ctx = (bf16*)(ws + off); off += E_IN * 2;

  cvt_w<<<dim3(4096), dim3(256), 0, stream>>>(Wq, Wk, Wv, Wo, Wqb, Wkb, Wvb, Wob);

  proj_qkv<<<dim3(32, 8, 3), dim3(512), 0, stream>>>(q, k, v, Wqb, Wkb, Wvb,
                                                     bq, bk, bv, Qh, Kh, Vtw);

  attn_fwd<<<dim3(1024), dim3(256), 0, stream>>>(Qh, Kh, Vtw, ctx);

  gemm_out<<<dim3(32, 8), dim3(512), 0, stream>>>(ctx, Wob, bo, (float*)d_out);
}

// Round 20
// 190.207 us; speedup vs baseline: 1.7710x; 1.7710x over previous
//
#include <hip/hip_runtime.h>
#include <hip/hip_bf16.h>
#include <stdint.h>

#define B_ 4
#define T_ 2048
#define D_ 1024
#define H_ 16
#define DK_ 64
#define M_ (B_*T_)   // 8192

typedef __attribute__((ext_vector_type(8))) short bf16x8;
typedef __attribute__((ext_vector_type(4))) short bf16x4;
typedef __attribute__((ext_vector_type(4))) float f32x4;
typedef __hip_bfloat16 bf16;

__device__ __forceinline__ void gld_lds16(const bf16* g, bf16* l) {
  __builtin_amdgcn_global_load_lds((const __attribute__((address_space(1))) void*)g,
                                   (__attribute__((address_space(3))) void*)l,
                                   16, 0, 0);
}
__device__ __forceinline__ void gld_lds16f(const float* g, float* l) {
  __builtin_amdgcn_global_load_lds((const __attribute__((address_space(1))) void*)g,
                                   (__attribute__((address_space(3))) void*)l,
                                   16, 0, 0);
}

__device__ __forceinline__ short bfbits(float f) {
  union { bf16 h; short s; } u; u.h = __float2bfloat16(f); return u.s;
}

// ---------------------------------------------------------------------------
// fp32 -> bf16 convert, WEIGHTS ONLY (round-18 exact)
// ---------------------------------------------------------------------------
__global__ __launch_bounds__(256) void cvt_w(
    const float* __restrict__ wq, const float* __restrict__ wk,
    const float* __restrict__ wv, const float* __restrict__ wo,
    bf16* __restrict__ wqb, bf16* __restrict__ wkb,
    bf16* __restrict__ wvb, bf16* __restrict__ wob) {
  int gid = blockIdx.x * 256 + threadIdx.x;   // 0 .. 1048575 (float4 units)
  int s = gid >> 18, off = gid & 262143;
  const float* src = (s == 0) ? wq : (s == 1) ? wk : (s == 2) ? wv : wo;
  bf16* dst = (s == 0) ? wqb : (s == 1) ? wkb : (s == 2) ? wvb : wob;
  float4 val = reinterpret_cast<const float4*>(src)[off];
  union { ushort4 u; bf16 h[4]; } o;
  o.h[0] = __float2bfloat16(val.x);
  o.h[1] = __float2bfloat16(val.y);
  o.h[2] = __float2bfloat16(val.z);
  o.h[3] = __float2bfloat16(val.w);
  reinterpret_cast<ushort4*>(dst)[off] = o.u;
}

// ---------------------------------------------------------------------------
// Unified QKV projection (round-18 exact)
// ---------------------------------------------------------------------------
__global__ __launch_bounds__(512) void proj_qkv(
    const float* __restrict__ qf, const float* __restrict__ kf, const float* __restrict__ vf,
    const bf16* __restrict__ Wqb, const bf16* __restrict__ Wkb, const bf16* __restrict__ Wvb,
    const float* __restrict__ bq, const float* __restrict__ bk, const float* __restrict__ bv,
    bf16* __restrict__ Qh, bf16* __restrict__ Kh, bf16* __restrict__ Vt) {
  constexpr int K = 1024;
  constexpr int BK = 64;
  __shared__ __align__(16) bf16  As[256 * 64];
  __shared__ __align__(16) float Bsf[128 * 64];

  const int z = blockIdx.z;
  const bf16*  A  = (z == 0) ? Wqb : (z == 1) ? Wkb : Wvb;
  const float* Bf = (z == 0) ? qf : (z == 1) ? kf : vf;
  const float* bias = (z == 0) ? bq : (z == 1) ? bk : bv;
  bf16* out = (z == 0) ? Qh : (z == 1) ? Kh : Vt;
  const float scale = (z == 0) ? 0.125f * 1.4426950408889634f : 1.0f;

  const int bid = blockIdx.x + 32 * blockIdx.y;
  const int bm = bid >> 6;
  const int bn = bid & 63;

  const int tid = threadIdx.x;
  const int w = tid >> 6, l = tid & 63;
  const int wm = w >> 1, wn = w & 1;
  const int lr = l & 15, lk = l >> 4;

  f32x4 acc[4][4] = {};

  for (int k0 = 0; k0 < K; k0 += BK) {
#pragma unroll
    for (int i = 0; i < 4; ++i) {
      int p = i * 512 + tid;
      int row = p >> 3;
      int so = (p & 7) ^ (row & 7);
      gld_lds16(A + (size_t)(bm * 256 + row) * K + k0 + so * 8, &As[p * 8]);
    }
#pragma unroll
    for (int i = 0; i < 4; ++i) {
      int p = i * 512 + tid;
      int row = p >> 4;
      int sc = (p & 15) ^ (row & 15);
      gld_lds16f(Bf + (size_t)(bn * 128 + row) * K + k0 + sc * 4, &Bsf[p * 4]);
    }
    __syncthreads();

#pragma unroll
    for (int kk = 0; kk < 2; ++kk) {
      bf16x8 af[4], bfr[4];
#pragma unroll
      for (int m = 0; m < 4; ++m) {
        int row = wm * 64 + m * 16 + lr;
        int slot = (kk * 4 + lk) ^ (row & 7);
        af[m] = *reinterpret_cast<const bf16x8*>(&As[row * 64 + slot * 8]);
      }
#pragma unroll
      for (int n = 0; n < 4; ++n) {
        int trow = wn * 64 + n * 16 + lr;
        int c0 = kk * 8 + lk * 2;
        int s0 = c0 ^ (trow & 15);
        int s1 = (c0 + 1) ^ (trow & 15);
        f32x4 lo = *reinterpret_cast<const f32x4*>(&Bsf[trow * 64 + s0 * 4]);
        f32x4 hi = *reinterpret_cast<const f32x4*>(&Bsf[trow * 64 + s1 * 4]);
        bf16x8 bb;
        bb[0] = bfbits(lo[0]); bb[1] = bfbits(lo[1]);
        bb[2] = bfbits(lo[2]); bb[3] = bfbits(lo[3]);
        bb[4] = bfbits(hi[0]); bb[5] = bfbits(hi[1]);
        bb[6] = bfbits(hi[2]); bb[7] = bfbits(hi[3]);
        bfr[n] = bb;
      }
      __builtin_amdgcn_s_setprio(1);
#pragma unroll
      for (int m = 0; m < 4; ++m)
#pragma unroll
        for (int n = 0; n < 4; ++n)
          acc[m][n] = __builtin_amdgcn_mfma_f32_16x16x32_bf16(af[m], bfr[n], acc[m][n], 0, 0, 0);
      __builtin_amdgcn_s_setprio(0);
    }
    __syncthreads();
  }

  const int crow0 = bm * 256 + wm * 64;
  const int ccol0 = bn * 128 + wn * 64;
  if (z < 2) {
#pragma unroll
    for (int m = 0; m < 4; ++m) {
#pragma unroll
      for (int n = 0; n < 4; ++n) {
        const int row0 = crow0 + m * 16 + lk * 4;
        const int col = ccol0 + n * 16 + lr;
        bf16x4 pk;
#pragma unroll
        for (int r = 0; r < 4; ++r)
          pk[r] = bfbits((acc[m][n][r] + bias[row0 + r]) * scale);
        size_t idx = (((size_t)(col >> 11) * H_ + (row0 >> 6)) * T_ + (col & (T_ - 1))) * DK_ + (row0 & 63);
        *reinterpret_cast<bf16x4*>(&out[idx]) = pk;
      }
    }
  } else {
#pragma unroll
    for (int m = 0; m < 4; ++m) {
#pragma unroll
      for (int n = 0; n < 4; ++n) {
#pragma unroll
        for (int r = 0; r < 4; ++r) {
          const int row = crow0 + m * 16 + lk * 4 + r;
          const int col = ccol0 + n * 16 + lr;
          float vv = acc[m][n][r] + bias[row];
          size_t idx = (size_t)(col >> 11) * ((size_t)H_ * DK_ * T_) + (size_t)row * T_ + (col & (T_ - 1));
          out[idx] = __float2bfloat16(vv);
        }
      }
    }
  }
}

// ---------------------------------------------------------------------------
// Output GEMM (round-18 exact)
// ---------------------------------------------------------------------------
__global__ __launch_bounds__(512) void gemm_out(const bf16* __restrict__ A,
                                                const bf16* __restrict__ Bm,
                                                const float* __restrict__ bias,
                                                float* __restrict__ Cout) {
  constexpr int K = 1024;
  constexpr int BK = 64;
  __shared__ __align__(16) bf16 As[256 * BK];
  __shared__ __align__(16) bf16 Bs[128 * BK];

  const int bid = blockIdx.x + 32 * blockIdx.y;
  const int xcd = bid & 7, loc = bid >> 3;
  const int bm = xcd * 4 + (loc & 3);
  const int bn = loc >> 2;

  const int tid = threadIdx.x;
  const int w = tid >> 6, l = tid & 63;
  const int wm = w >> 1, wn = w & 1;
  const int lr = l & 15, lk = l >> 4;

  f32x4 acc[4][4] = {};

  for (int k0 = 0; k0 < K; k0 += BK) {
#pragma unroll
    for (int i = 0; i < 4; ++i) {
      int p = i * 512 + tid;
      int row = p >> 3;
      int so = (p & 7) ^ (row & 7);
      gld_lds16(A + (size_t)(bm * 256 + row) * K + k0 + so * 8, &As[p * 8]);
    }
#pragma unroll
    for (int i = 0; i < 2; ++i) {
      int p = i * 512 + tid;
      int row = p >> 3;
      int so = (p & 7) ^ (row & 7);
      gld_lds16(Bm + (size_t)(bn * 128 + row) * K + k0 + so * 8, &Bs[p * 8]);
    }
    __syncthreads();

#pragma unroll
    for (int kk = 0; kk < 2; ++kk) {
      bf16x8 af[4], bfr[4];
#pragma unroll
      for (int m = 0; m < 4; ++m) {
        int row = wm * 64 + m * 16 + lr;
        int slot = (kk * 4 + lk) ^ (row & 7);
        af[m] = *reinterpret_cast<const bf16x8*>(&As[row * BK + slot * 8]);
      }
#pragma unroll
      for (int n = 0; n < 4; ++n) {
        int row = wn * 64 + n * 16 + lr;
        int slot = (kk * 4 + lk) ^ (row & 7);
        bfr[n] = *reinterpret_cast<const bf16x8*>(&Bs[row * BK + slot * 8]);
      }
#pragma unroll
      for (int m = 0; m < 4; ++m)
#pragma unroll
        for (int n = 0; n < 4; ++n)
          acc[m][n] = __builtin_amdgcn_mfma_f32_16x16x32_bf16(af[m], bfr[n], acc[m][n], 0, 0, 0);
    }
    __syncthreads();
  }

  const int crow0 = bm * 256 + wm * 64;
  const int ccol0 = bn * 128 + wn * 64;
#pragma unroll
  for (int m = 0; m < 4; ++m) {
#pragma unroll
    for (int n = 0; n < 4; ++n) {
#pragma unroll
      for (int r = 0; r < 4; ++r) {
        const int row = crow0 + m * 16 + lk * 4 + r;
        const int col = ccol0 + n * 16 + lr;
        Cout[(size_t)row * D_ + col] = acc[m][n][r] + bias[col];
      }
    }
  }
}

// ---------------------------------------------------------------------------
// Causal flash attention v14b: TWO 16-row groups per wave, KVBLK=32.
// Identical to round-19 v14 EXCEPT __launch_bounds__(256,4): round-19's
// (256,6) capped VGPR at ~85 -> accumulator spill to scratch (WRITE_SIZE
// 16->167 MB, 3x slowdown). (256,4) caps at 128 VGPR: no spill, ~4 blocks/CU
// = same occupancy as the r12 baseline but with barriers / staging issues /
// K/V fragment reads halved per unit work (shared across both groups).
// ---------------------------------------------------------------------------
__global__ __launch_bounds__(256, 4) void attn_fwd(const bf16* __restrict__ Qh,
                                                   const bf16* __restrict__ Kh,
                                                   const bf16* __restrict__ Vt,
                                                   bf16* __restrict__ ctx) {
  __shared__ __align__(16) bf16 Kbuf[2][32 * 64];   // 8 KB
  __shared__ __align__(16) bf16 Vbuf[2][32 * 64];   // 8 KB (packed 2 dk/row)
  __shared__ __align__(16) char Ps[4][2][16 * 80];  // 10 KB

  const int tid = threadIdx.x, w = tid >> 6, l = tid & 63;
  const int lr = l & 15, lk = l >> 4;
  const int bid = blockIdx.x;
  const int head = bid & 63;                 // head%8 == bid%8 -> XCD pinning
  const int t = 15 - (bid >> 6);             // heavy tasks first (128 rows each)

  const bf16* Qb = Qh + (size_t)head * T_ * DK_;
  const bf16* Kb = Kh + (size_t)head * T_ * DK_;
  const bf16* Vb = Vt + (size_t)head * DK_ * T_;
  const int bb = head >> 4, hh = head & 15;

  const int base = t * 128 + w * 32;         // this wave's 32 q-rows
  const int nt32 = 4 * (t + 1);              // KV tiles of 32
  const int jd = base >> 5;                  // shared diagonal tile

  // ---- Q fragments, both groups ----
  bf16x8 qf[2][2];
#pragma unroll
  for (int g = 0; g < 2; ++g) {
    const bf16* qp = Qb + (size_t)(base + g * 16 + lr) * DK_ + lk * 8;
    qf[g][0] = *reinterpret_cast<const bf16x8*>(qp);
    qf[g][1] = *reinterpret_cast<const bf16x8*>(qp + 32);
  }

  // ---- hoisted staging pointers ----
  const int p = tid;
  const int krow = p >> 3, kso = (p & 7) ^ (krow & 7);
  const bf16* kgp = Kb + (size_t)krow * DK_ + kso * 8;
  const int vu = (p & 7) ^ (krow & 7);
  const int vdk = krow * 2 + (vu >> 2);
  const bf16* vgp = Vb + (size_t)vdk * T_ + (vu & 3) * 8;
  bf16* const kl0 = &Kbuf[0][p * 8];
  bf16* const kl1 = &Kbuf[1][p * 8];
  bf16* const vl0 = &Vbuf[0][p * 8];
  bf16* const vl1 = &Vbuf[1][p * 8];

  // ---- hoisted fragment/P offsets ----
  int qko[2][2], pvo[4];
#pragma unroll
  for (int n = 0; n < 2; ++n) {
    const int row = n * 16 + lr;
    qko[n][0] = row * 64 + ((lk ^ (row & 7)) << 3);
    qko[n][1] = row * 64 + (((4 + lk) ^ (row & 7)) << 3);
  }
#pragma unroll
  for (int n = 0; n < 4; ++n) {
    const int rowp = n * 8 + (lr >> 1);
    const int s = ((lr & 1) * 4 + lk) ^ (rowp & 7);
    pvo[n] = rowp * 64 + s * 8;
  }
  char* const Pw0 = &Ps[w][0][0];
  char* const Pw1 = &Ps[w][1][0];
  const int pro = lr * 80 + lk * 16;

  f32x4 oacc[2][4] = {};
  float srow[2] = { 0.f, 0.f };

  // ---- prologue ----
  gld_lds16(kgp, kl0);
  gld_lds16(vgp, vl0);
  kgp += 32 * DK_;
  vgp += 32;
  __syncthreads();

  int buf = 0;
#pragma unroll 1
  for (int j = 0; j < nt32; ++j) {
    if (j + 1 < nt32) {
      gld_lds16(kgp, buf ? kl0 : kl1);
      gld_lds16(vgp, buf ? vl0 : vl1);
      kgp += 32 * DK_;
      vgp += 32;
    }

    if (j <= jd) {
      const bf16* kbase = buf ? &Kbuf[1][0] : &Kbuf[0][0];
      const bf16* vbase = buf ? &Vbuf[1][0] : &Vbuf[0][0];

      // ---- S^T: K fragments shared across both groups ----
      f32x4 sacc[2][2] = {};
      __builtin_amdgcn_s_setprio(1);
#pragma unroll
      for (int n = 0; n < 2; ++n) {
        bf16x8 kf0 = *reinterpret_cast<const bf16x8*>(kbase + qko[n][0]);
        bf16x8 kf1 = *reinterpret_cast<const bf16x8*>(kbase + qko[n][1]);
        sacc[0][n] = __builtin_amdgcn_mfma_f32_16x16x32_bf16(kf0, qf[0][0], sacc[0][n], 0, 0, 0);
        sacc[0][n] = __builtin_amdgcn_mfma_f32_16x16x32_bf16(kf1, qf[0][1], sacc[0][n], 0, 0, 0);
        sacc[1][n] = __builtin_amdgcn_mfma_f32_16x16x32_bf16(kf0, qf[1][0], sacc[1][n], 0, 0, 0);
        sacc[1][n] = __builtin_amdgcn_mfma_f32_16x16x32_bf16(kf1, qf[1][1], sacc[1][n], 0, 0, 0);
      }
      __builtin_amdgcn_s_setprio(0);

      // ---- causal mask on the shared diagonal tile ----
      if (j == jd) {
#pragma unroll
        for (int g = 0; g < 2; ++g) {
          const int qrow = base + g * 16 + lr;
#pragma unroll
          for (int n = 0; n < 2; ++n)
#pragma unroll
            for (int r = 0; r < 4; ++r)
              if (j * 32 + n * 16 + lk * 4 + r > qrow) sacc[g][n][r] = -1e30f;
        }
      }

      // ---- fixed-shift softmax per group ----
      bf16x8 pa[2];
#pragma unroll
      for (int g = 0; g < 2; ++g) {
        char* Pw = g ? Pw1 : Pw0;
        float ts = 0.f;
#pragma unroll
        for (int n = 0; n < 2; ++n) {
          float p0 = __builtin_exp2f(sacc[g][n][0]);
          float p1 = __builtin_exp2f(sacc[g][n][1]);
          float p2 = __builtin_exp2f(sacc[g][n][2]);
          float p3 = __builtin_exp2f(sacc[g][n][3]);
          ts += (p0 + p1) + (p2 + p3);
          bf16x4 pk;
          pk[0] = bfbits(p0); pk[1] = bfbits(p1); pk[2] = bfbits(p2); pk[3] = bfbits(p3);
          *reinterpret_cast<bf16x4*>(Pw + lr * 80 + n * 32 + lk * 8) = pk;
        }
        ts += __shfl_xor(ts, 16, 64);
        ts += __shfl_xor(ts, 32, 64);
        srow[g] += ts;
        pa[g] = *reinterpret_cast<const bf16x8*>(Pw + pro);
      }

      // ---- PV: V fragments shared across both groups ----
      __builtin_amdgcn_s_setprio(1);
#pragma unroll
      for (int n = 0; n < 4; ++n) {
        bf16x8 vf = *reinterpret_cast<const bf16x8*>(vbase + pvo[n]);
        oacc[0][n] = __builtin_amdgcn_mfma_f32_16x16x32_bf16(vf, pa[0], oacc[0][n], 0, 0, 0);
        oacc[1][n] = __builtin_amdgcn_mfma_f32_16x16x32_bf16(vf, pa[1], oacc[1][n], 0, 0, 0);
      }
      __builtin_amdgcn_s_setprio(0);
    }

    __syncthreads();
    buf ^= 1;
  }

  // ---- normalize + packed store (both groups) ----
#pragma unroll
  for (int g = 0; g < 2; ++g) {
    const float inv = 1.0f / srow[g];
    bf16* cp = &ctx[((size_t)(bb * T_ + base + g * 16 + lr)) * D_ + hh * DK_ + lk * 4];
#pragma unroll
    for (int n = 0; n < 4; ++n) {
      bf16x4 pk;
#pragma unroll
      for (int r = 0; r < 4; ++r) pk[r] = bfbits(oacc[g][n][r] * inv);
      *reinterpret_cast<bf16x4*>(cp + n * 16) = pk;
    }
  }
}

// ---------------------------------------------------------------------------
// launch
// ---------------------------------------------------------------------------
extern "C" void kernel_launch(void* const* d_in, const int* in_sizes, int n_in,
                              void* d_out, int out_size, void* d_ws, size_t ws_size,
                              hipStream_t stream) {
  const float* q  = (const float*)d_in[0];
  const float* k  = (const float*)d_in[1];
  const float* v  = (const float*)d_in[2];
  const float* Wq = (const float*)d_in[3];
  const float* Wk = (const float*)d_in[4];
  const float* Wv = (const float*)d_in[5];
  const float* Wo = (const float*)d_in[6];
  const float* bq = (const float*)d_in[7];
  const float* bk = (const float*)d_in[8];
  const float* bv = (const float*)d_in[9];
  const float* bo = (const float*)d_in[10];

  constexpr size_t E_IN = (size_t)M_ * D_;
  constexpr size_t E_W  = (size_t)D_ * D_;
  char* ws = (char*)d_ws;
  size_t off = 0;
  bf16* Wqb = (bf16*)(ws + off); off += E_W * 2;
  bf16* Wkb = (bf16*)(ws + off); off += E_W * 2;
  bf16* Wvb = (bf16*)(ws + off); off += E_W * 2;
  bf16* Wob = (bf16*)(ws + off); off += E_W * 2;
  bf16* Qh  = (bf16*)(ws + off); off += E_IN * 2;
  bf16* Kh  = (bf16*)(ws + off); off += E_IN * 2;
  bf16* Vtw = (bf16*)(ws + off); off += E_IN * 2;
  bf16* ctx = (bf16*)(ws + off); off += E_IN * 2;

  cvt_w<<<dim3(4096), dim3(256), 0, stream>>>(Wq, Wk, Wv, Wo, Wqb, Wkb, Wvb, Wob);

  proj_qkv<<<dim3(32, 8, 3), dim3(512), 0, stream>>>(q, k, v, Wqb, Wkb, Wvb,
                                                     bq, bk, bv, Qh, Kh, Vtw);

  attn_fwd<<<dim3(1024), dim3(256), 0, stream>>>(Qh, Kh, Vtw, ctx);

  gemm_out<<<dim3(32, 8), dim3(512), 0, stream>>>(ctx, Wob, bo, (float*)d_out);
}

// Round 21
// 184.277 us; speedup vs baseline: 1.8280x; 1.0322x over previous
//
#include <hip/hip_runtime.h>
#include <hip/hip_bf16.h>
#include <stdint.h>

#define B_ 4
#define T_ 2048
#define D_ 1024
#define H_ 16
#define DK_ 64
#define M_ (B_*T_)   // 8192

typedef __attribute__((ext_vector_type(8))) short bf16x8;
typedef __attribute__((ext_vector_type(4))) short bf16x4;
typedef __attribute__((ext_vector_type(4))) float f32x4;
typedef __hip_bfloat16 bf16;

__device__ __forceinline__ void gld_lds16(const bf16* g, bf16* l) {
  __builtin_amdgcn_global_load_lds((const __attribute__((address_space(1))) void*)g,
                                   (__attribute__((address_space(3))) void*)l,
                                   16, 0, 0);
}
__device__ __forceinline__ void gld_lds16f(const float* g, float* l) {
  __builtin_amdgcn_global_load_lds((const __attribute__((address_space(1))) void*)g,
                                   (__attribute__((address_space(3))) void*)l,
                                   16, 0, 0);
}

__device__ __forceinline__ short bfbits(float f) {
  union { bf16 h; short s; } u; u.h = __float2bfloat16(f); return u.s;
}

// ---------------------------------------------------------------------------
// fp32 -> bf16 convert, WEIGHTS ONLY (round-18 exact)
// ---------------------------------------------------------------------------
__global__ __launch_bounds__(256) void cvt_w(
    const float* __restrict__ wq, const float* __restrict__ wk,
    const float* __restrict__ wv, const float* __restrict__ wo,
    bf16* __restrict__ wqb, bf16* __restrict__ wkb,
    bf16* __restrict__ wvb, bf16* __restrict__ wob) {
  int gid = blockIdx.x * 256 + threadIdx.x;   // 0 .. 1048575 (float4 units)
  int s = gid >> 18, off = gid & 262143;
  const float* src = (s == 0) ? wq : (s == 1) ? wk : (s == 2) ? wv : wo;
  bf16* dst = (s == 0) ? wqb : (s == 1) ? wkb : (s == 2) ? wvb : wob;
  float4 val = reinterpret_cast<const float4*>(src)[off];
  union { ushort4 u; bf16 h[4]; } o;
  o.h[0] = __float2bfloat16(val.x);
  o.h[1] = __float2bfloat16(val.y);
  o.h[2] = __float2bfloat16(val.z);
  o.h[3] = __float2bfloat16(val.w);
  reinterpret_cast<ushort4*>(dst)[off] = o.u;
}

// ---------------------------------------------------------------------------
// Unified QKV projection (round-18 exact): (feature, token) orientation,
// A = weight bf16 via gld_lds, B = raw fp32 tokens via gld_lds, converted
// per-fragment. 2-phase sync. LDS 64 KB.
// ---------------------------------------------------------------------------
__global__ __launch_bounds__(512) void proj_qkv(
    const float* __restrict__ qf, const float* __restrict__ kf, const float* __restrict__ vf,
    const bf16* __restrict__ Wqb, const bf16* __restrict__ Wkb, const bf16* __restrict__ Wvb,
    const float* __restrict__ bq, const float* __restrict__ bk, const float* __restrict__ bv,
    bf16* __restrict__ Qh, bf16* __restrict__ Kh, bf16* __restrict__ Vt) {
  constexpr int K = 1024;
  constexpr int BK = 64;
  __shared__ __align__(16) bf16  As[256 * 64];
  __shared__ __align__(16) float Bsf[128 * 64];

  const int z = blockIdx.z;
  const bf16*  A  = (z == 0) ? Wqb : (z == 1) ? Wkb : Wvb;
  const float* Bf = (z == 0) ? qf : (z == 1) ? kf : vf;
  const float* bias = (z == 0) ? bq : (z == 1) ? bk : bv;
  bf16* out = (z == 0) ? Qh : (z == 1) ? Kh : Vt;
  const float scale = (z == 0) ? 0.125f * 1.4426950408889634f : 1.0f;

  const int bid = blockIdx.x + 32 * blockIdx.y;
  const int bm = bid >> 6;
  const int bn = bid & 63;

  const int tid = threadIdx.x;
  const int w = tid >> 6, l = tid & 63;
  const int wm = w >> 1, wn = w & 1;
  const int lr = l & 15, lk = l >> 4;

  f32x4 acc[4][4] = {};

  for (int k0 = 0; k0 < K; k0 += BK) {
#pragma unroll
    for (int i = 0; i < 4; ++i) {
      int p = i * 512 + tid;
      int row = p >> 3;
      int so = (p & 7) ^ (row & 7);
      gld_lds16(A + (size_t)(bm * 256 + row) * K + k0 + so * 8, &As[p * 8]);
    }
#pragma unroll
    for (int i = 0; i < 4; ++i) {
      int p = i * 512 + tid;
      int row = p >> 4;
      int sc = (p & 15) ^ (row & 15);
      gld_lds16f(Bf + (size_t)(bn * 128 + row) * K + k0 + sc * 4, &Bsf[p * 4]);
    }
    __syncthreads();

#pragma unroll
    for (int kk = 0; kk < 2; ++kk) {
      bf16x8 af[4], bfr[4];
#pragma unroll
      for (int m = 0; m < 4; ++m) {
        int row = wm * 64 + m * 16 + lr;
        int slot = (kk * 4 + lk) ^ (row & 7);
        af[m] = *reinterpret_cast<const bf16x8*>(&As[row * 64 + slot * 8]);
      }
#pragma unroll
      for (int n = 0; n < 4; ++n) {
        int trow = wn * 64 + n * 16 + lr;
        int c0 = kk * 8 + lk * 2;
        int s0 = c0 ^ (trow & 15);
        int s1 = (c0 + 1) ^ (trow & 15);
        f32x4 lo = *reinterpret_cast<const f32x4*>(&Bsf[trow * 64 + s0 * 4]);
        f32x4 hi = *reinterpret_cast<const f32x4*>(&Bsf[trow * 64 + s1 * 4]);
        bf16x8 bb;
        bb[0] = bfbits(lo[0]); bb[1] = bfbits(lo[1]);
        bb[2] = bfbits(lo[2]); bb[3] = bfbits(lo[3]);
        bb[4] = bfbits(hi[0]); bb[5] = bfbits(hi[1]);
        bb[6] = bfbits(hi[2]); bb[7] = bfbits(hi[3]);
        bfr[n] = bb;
      }
      __builtin_amdgcn_s_setprio(1);
#pragma unroll
      for (int m = 0; m < 4; ++m)
#pragma unroll
        for (int n = 0; n < 4; ++n)
          acc[m][n] = __builtin_amdgcn_mfma_f32_16x16x32_bf16(af[m], bfr[n], acc[m][n], 0, 0, 0);
      __builtin_amdgcn_s_setprio(0);
    }
    __syncthreads();
  }

  const int crow0 = bm * 256 + wm * 64;
  const int ccol0 = bn * 128 + wn * 64;
  if (z < 2) {
#pragma unroll
    for (int m = 0; m < 4; ++m) {
#pragma unroll
      for (int n = 0; n < 4; ++n) {
        const int row0 = crow0 + m * 16 + lk * 4;
        const int col = ccol0 + n * 16 + lr;
        bf16x4 pk;
#pragma unroll
        for (int r = 0; r < 4; ++r)
          pk[r] = bfbits((acc[m][n][r] + bias[row0 + r]) * scale);
        size_t idx = (((size_t)(col >> 11) * H_ + (row0 >> 6)) * T_ + (col & (T_ - 1))) * DK_ + (row0 & 63);
        *reinterpret_cast<bf16x4*>(&out[idx]) = pk;
      }
    }
  } else {
#pragma unroll
    for (int m = 0; m < 4; ++m) {
#pragma unroll
      for (int n = 0; n < 4; ++n) {
#pragma unroll
        for (int r = 0; r < 4; ++r) {
          const int row = crow0 + m * 16 + lk * 4 + r;
          const int col = ccol0 + n * 16 + lr;
          float vv = acc[m][n][r] + bias[row];
          size_t idx = (size_t)(col >> 11) * ((size_t)H_ * DK_ * T_) + (size_t)row * T_ + (col & (T_ - 1));
          out[idx] = __float2bfloat16(vv);
        }
      }
    }
  }
}

// ---------------------------------------------------------------------------
// Output GEMM (round-18 exact)
// ---------------------------------------------------------------------------
__global__ __launch_bounds__(512) void gemm_out(const bf16* __restrict__ A,
                                                const bf16* __restrict__ Bm,
                                                const float* __restrict__ bias,
                                                float* __restrict__ Cout) {
  constexpr int K = 1024;
  constexpr int BK = 64;
  __shared__ __align__(16) bf16 As[256 * BK];
  __shared__ __align__(16) bf16 Bs[128 * BK];

  const int bid = blockIdx.x + 32 * blockIdx.y;
  const int xcd = bid & 7, loc = bid >> 3;
  const int bm = xcd * 4 + (loc & 3);
  const int bn = loc >> 2;

  const int tid = threadIdx.x;
  const int w = tid >> 6, l = tid & 63;
  const int wm = w >> 1, wn = w & 1;
  const int lr = l & 15, lk = l >> 4;

  f32x4 acc[4][4] = {};

  for (int k0 = 0; k0 < K; k0 += BK) {
#pragma unroll
    for (int i = 0; i < 4; ++i) {
      int p = i * 512 + tid;
      int row = p >> 3;
      int so = (p & 7) ^ (row & 7);
      gld_lds16(A + (size_t)(bm * 256 + row) * K + k0 + so * 8, &As[p * 8]);
    }
#pragma unroll
    for (int i = 0; i < 2; ++i) {
      int p = i * 512 + tid;
      int row = p >> 3;
      int so = (p & 7) ^ (row & 7);
      gld_lds16(Bm + (size_t)(bn * 128 + row) * K + k0 + so * 8, &Bs[p * 8]);
    }
    __syncthreads();

#pragma unroll
    for (int kk = 0; kk < 2; ++kk) {
      bf16x8 af[4], bfr[4];
#pragma unroll
      for (int m = 0; m < 4; ++m) {
        int row = wm * 64 + m * 16 + lr;
        int slot = (kk * 4 + lk) ^ (row & 7);
        af[m] = *reinterpret_cast<const bf16x8*>(&As[row * BK + slot * 8]);
      }
#pragma unroll
      for (int n = 0; n < 4; ++n) {
        int row = wn * 64 + n * 16 + lr;
        int slot = (kk * 4 + lk) ^ (row & 7);
        bfr[n] = *reinterpret_cast<const bf16x8*>(&Bs[row * BK + slot * 8]);
      }
#pragma unroll
      for (int m = 0; m < 4; ++m)
#pragma unroll
        for (int n = 0; n < 4; ++n)
          acc[m][n] = __builtin_amdgcn_mfma_f32_16x16x32_bf16(af[m], bfr[n], acc[m][n], 0, 0, 0);
    }
    __syncthreads();
  }

  const int crow0 = bm * 256 + wm * 64;
  const int ccol0 = bn * 128 + wn * 64;
#pragma unroll
  for (int m = 0; m < 4; ++m) {
#pragma unroll
    for (int n = 0; n < 4; ++n) {
#pragma unroll
      for (int r = 0; r < 4; ++r) {
        const int row = crow0 + m * 16 + lk * 4 + r;
        const int col = ccol0 + n * 16 + lr;
        Cout[(size_t)row * D_ + col] = acc[m][n][r] + bias[col];
      }
    }
  }
}

// ---------------------------------------------------------------------------
// Causal flash attention v15: r18's v13 skeleton (7 blocks/CU, KVBLK=32,
// hoisted addressing) + DEFERRED srow reduction: with fixed-shift softmax,
// srow is a pure linear sum, so each lane keeps a private partial and the
// 2 cross-lane shuffles run ONCE after the loop instead of per tile-iter
// (removes 2 serial ds_bpermute from every iteration's critical path).
// ---------------------------------------------------------------------------
__global__ __launch_bounds__(256, 7) void attn_fwd(const bf16* __restrict__ Qh,
                                                   const bf16* __restrict__ Kh,
                                                   const bf16* __restrict__ Vt,
                                                   bf16* __restrict__ ctx) {
  __shared__ __align__(16) bf16 Kbuf[2][32 * 64];
  __shared__ __align__(16) bf16 Vbuf[2][32 * 64];
  __shared__ __align__(16) char Ps[4][16 * 80];

  const int tid = threadIdx.x, w = tid >> 6, l = tid & 63;
  const int lr = l & 15, lk = l >> 4;
  const int bid = blockIdx.x;
  const int head = bid & 63;
  const int t = 31 - (bid >> 6);
  char* Pw = &Ps[w][0];

  const bf16* Qb = Qh + (size_t)head * T_ * DK_;
  const bf16* Kb = Kh + (size_t)head * T_ * DK_;
  const bf16* Vb = Vt + (size_t)head * DK_ * T_;
  const int bb = head >> 4, hh = head & 15;

  const int r0 = t * 64;
  const int nt32 = 2 * (t + 1);
  const int qrow = r0 + w * 16 + lr;
  const int jd = (r0 + w * 16) >> 5;

  const bf16* qp = Qb + (size_t)qrow * DK_ + lk * 8;
  bf16x8 qf0 = *reinterpret_cast<const bf16x8*>(qp);
  bf16x8 qf1 = *reinterpret_cast<const bf16x8*>(qp + 32);

  // hoisted staging pointers
  const int p = tid;
  const int krow = p >> 3, kso = (p & 7) ^ (krow & 7);
  const bf16* kgp = Kb + (size_t)krow * DK_ + kso * 8;
  const int vu = (p & 7) ^ (krow & 7);
  const int vdk = krow * 2 + (vu >> 2);
  const bf16* vgp = Vb + (size_t)vdk * T_ + (vu & 3) * 8;
  bf16* const kl0 = &Kbuf[0][p * 8];
  bf16* const kl1 = &Kbuf[1][p * 8];
  bf16* const vl0 = &Vbuf[0][p * 8];
  bf16* const vl1 = &Vbuf[1][p * 8];

  // hoisted fragment/P offsets
  int qko[2][2], pwo[2], pvo[4];
#pragma unroll
  for (int n = 0; n < 2; ++n) {
    const int row = n * 16 + lr;
    qko[n][0] = row * 64 + ((lk ^ (row & 7)) << 3);
    qko[n][1] = row * 64 + (((4 + lk) ^ (row & 7)) << 3);
    pwo[n] = lr * 80 + n * 32 + lk * 8;
  }
  const int pro = lr * 80 + lk * 16;
#pragma unroll
  for (int n = 0; n < 4; ++n) {
    const int rowp = n * 8 + (lr >> 1);
    const int s = ((lr & 1) * 4 + lk) ^ (rowp & 7);
    pvo[n] = rowp * 64 + s * 8;
  }
  bf16* const cp = &ctx[((size_t)(bb * T_ + qrow)) * D_ + hh * DK_ + lk * 4];

  f32x4 oacc[4] = {};
  float srow = 0.f;                            // private partial (deferred reduce)

  // prologue: stage tile 0
  gld_lds16(kgp, kl0);
  gld_lds16(vgp, vl0);
  kgp += 32 * DK_;
  vgp += 32;
  __syncthreads();

  int buf = 0;
#pragma unroll 1
  for (int j = 0; j < nt32; ++j) {
    if (j + 1 < nt32) {
      gld_lds16(kgp, buf ? kl0 : kl1);
      gld_lds16(vgp, buf ? vl0 : vl1);
      kgp += 32 * DK_;
      vgp += 32;
    }

    if (j <= jd) {
      const bf16* kbase = buf ? &Kbuf[1][0] : &Kbuf[0][0];
      const bf16* vbase = buf ? &Vbuf[1][0] : &Vbuf[0][0];

      f32x4 sacc[2] = {};
      __builtin_amdgcn_s_setprio(1);
#pragma unroll
      for (int n = 0; n < 2; ++n) {
        bf16x8 kf0 = *reinterpret_cast<const bf16x8*>(kbase + qko[n][0]);
        bf16x8 kf1 = *reinterpret_cast<const bf16x8*>(kbase + qko[n][1]);
        sacc[n] = __builtin_amdgcn_mfma_f32_16x16x32_bf16(kf0, qf0, sacc[n], 0, 0, 0);
        sacc[n] = __builtin_amdgcn_mfma_f32_16x16x32_bf16(kf1, qf1, sacc[n], 0, 0, 0);
      }
      __builtin_amdgcn_s_setprio(0);

      if (j == jd) {
#pragma unroll
        for (int n = 0; n < 2; ++n)
#pragma unroll
          for (int r = 0; r < 4; ++r)
            if (j * 32 + n * 16 + lk * 4 + r > qrow) sacc[n][r] = -1e30f;
      }

#pragma unroll
      for (int n = 0; n < 2; ++n) {
        float p0 = __builtin_exp2f(sacc[n][0]);
        float p1 = __builtin_exp2f(sacc[n][1]);
        float p2 = __builtin_exp2f(sacc[n][2]);
        float p3 = __builtin_exp2f(sacc[n][3]);
        srow += (p0 + p1) + (p2 + p3);         // private partial; no shuffles here
        bf16x4 pk;
        pk[0] = bfbits(p0); pk[1] = bfbits(p1); pk[2] = bfbits(p2); pk[3] = bfbits(p3);
        *reinterpret_cast<bf16x4*>(Pw + pwo[n]) = pk;
      }

      bf16x8 pa = *reinterpret_cast<const bf16x8*>(Pw + pro);

      __builtin_amdgcn_s_setprio(1);
#pragma unroll
      for (int n = 0; n < 4; ++n) {
        bf16x8 vf = *reinterpret_cast<const bf16x8*>(vbase + pvo[n]);
        oacc[n] = __builtin_amdgcn_mfma_f32_16x16x32_bf16(vf, pa, oacc[n], 0, 0, 0);
      }
      __builtin_amdgcn_s_setprio(0);
    }

    __syncthreads();
    buf ^= 1;
  }

  // deferred cross-lane reduction (once per task, not per tile)
  srow += __shfl_xor(srow, 16, 64);
  srow += __shfl_xor(srow, 32, 64);

  const float inv = 1.0f / srow;
#pragma unroll
  for (int n = 0; n < 4; ++n) {
    bf16x4 pk;
#pragma unroll
    for (int r = 0; r < 4; ++r) pk[r] = bfbits(oacc[n][r] * inv);
    *reinterpret_cast<bf16x4*>(cp + n * 16) = pk;
  }
}

// ---------------------------------------------------------------------------
// launch
// ---------------------------------------------------------------------------
extern "C" void kernel_launch(void* const* d_in, const int* in_sizes, int n_in,
                              void* d_out, int out_size, void* d_ws, size_t ws_size,
                              hipStream_t stream) {
  const float* q  = (const float*)d_in[0];
  const float* k  = (const float*)d_in[1];
  const float* v  = (const float*)d_in[2];
  const float* Wq = (const float*)d_in[3];
  const float* Wk = (const float*)d_in[4];
  const float* Wv = (const float*)d_in[5];
  const float* Wo = (const float*)d_in[6];
  const float* bq = (const float*)d_in[7];
  const float* bk = (const float*)d_in[8];
  const float* bv = (const float*)d_in[9];
  const float* bo = (const float*)d_in[10];

  constexpr size_t E_IN = (size_t)M_ * D_;
  constexpr size_t E_W  = (size_t)D_ * D_;
  char* ws = (char*)d_ws;
  size_t off = 0;
  bf16* Wqb = (bf16*)(ws + off); off += E_W * 2;
  bf16* Wkb = (bf16*)(ws + off); off += E_W * 2;
  bf16* Wvb = (bf16*)(ws + off); off += E_W * 2;
  bf16* Wob = (bf16*)(ws + off); off += E_W * 2;
  bf16* Qh  = (bf16*)(ws + off); off += E_IN * 2;
  bf16* Kh  = (bf16*)(ws + off); off += E_IN * 2;
  bf16* Vtw = (bf16*)(ws + off); off += E_IN * 2;
  bf16* ctx = (bf16*)(ws + off); off += E_IN * 2;

  cvt_w<<<dim3(4096), dim3(256), 0, stream>>>(Wq, Wk, Wv, Wo, Wqb, Wkb, Wvb, Wob);

  proj_qkv<<<dim3(32, 8, 3), dim3(512), 0, stream>>>(q, k, v, Wqb, Wkb, Wvb,
                                                     bq, bk, bv, Qh, Kh, Vtw);

  attn_fwd<<<dim3(2048), dim3(256), 0, stream>>>(Qh, Kh, Vtw, ctx);

  gemm_out<<<dim3(32, 8), dim3(512), 0, stream>>>(ctx, Wob, bo, (float*)d_out);
}